// Round 2
// baseline (121.032 us; speedup 1.0000x reference)
//
#include <hip/hip_runtime.h>
#include <math.h>

// DirectionalContrastiveLoss — N=8, C=192, H=W=112, T=0.1
//
// R8: exact-fit grid + vertical 2-px register blocking.
//  - tile 7x56 (+halo = 9x58): grid (2,16,8) = 256 blocks = exactly 1 block/CU
//    (R7: 448 blocks @ 2/CU capacity -> 2-round tail, ~14% loss).
//  - NT=1024, two 512-thread channel-halves (ch 0..95 / 96..191).
//  - compute threads own a vertical PIXEL PAIR (rows 2p,2p+1; last pair (5,6)
//    discards its duplicated row-5): 4-row x 3-col window = 12 ds_read_b128
//    per group for 2 px vs 18 (LDS read pipe 13.2 -> ~10 us).
//  - halo factor 1.55 -> 1.33.
//  - KCH=8 double-buffered as in R7 (12 barriers), v_pk_fma_f32 accumulation,
//    center self-dot from staged norm partials (ssp).

namespace {
constexpr int N_ = 8, C_ = 192, H_ = 112, W_ = 112;
constexpr int HW = H_ * W_;
constexpr int TH = 7;                  // pixel rows per block
constexpr int WS = 56;                 // pixel cols per block
constexpr int TROWS = TH + 2;          // 9
constexpr int TCOLS = WS + 2;          // 58
constexpr int TILE_E = TROWS * TCOLS;  // 522
constexpr int NT2 = 512;               // threads per channel-half
constexpr int NT = 2 * NT2;            // 1024
constexpr int NPAIR = 4 * WS;          // 224 compute (pair) threads per half
constexpr int EXTRA = TILE_E - NT2;    // 10 threads own a 2nd staging slot
constexpr int CHALF = C_ / 2;          // 96 channels per half
constexpr int KCH = 8;                 // channels per chunk (per half)
constexpr int GRP = KCH / 4;           // 2 float4 groups
constexpr int NCHUNK = CHALF / KCH;    // 12 chunks -> 12 barriers
constexpr int NBLK = (W_ / WS) * (H_ / TH) * N_;  // 2*16*8 = 256
constexpr float INV_T = 10.0f;
constexpr double TOTAL = (double)N_ * N_ * H_ * W_;  // 802816
}

typedef float v2f __attribute__((ext_vector_type(2)));
typedef float v4f __attribute__((ext_vector_type(4)));

__device__ __forceinline__ void pkfma(v2f& a, v2f x, v2f y) {
    asm("v_pk_fma_f32 %0, %1, %2, %0" : "+v"(a) : "v"(x), "v"(y));
}

__device__ __forceinline__ float sel3(int d, float a, float b, float c) {
    float r = (d < 0) ? a : b;
    return (d > 0) ? c : r;
}

extern "C" __global__ void __launch_bounds__(NT)
dcl_main(const float* __restrict__ feat,
         const int* __restrict__ labels,
         const int* __restrict__ dirs,
         double* __restrict__ partial, int use_partial)
{
    __shared__ v4f   tiles[2][2][GRP][TILE_E];  // [half][dbuf][grp] = 65.3 KB
    __shared__ float ssp[2][TILE_E];            // per-half norm partials, 4.2 KB
    __shared__ float ssbuf[TILE_E];             // combined inv-norms, 2.1 KB
    __shared__ float scomb[TH * WS][9];         // half1 dot partials (pad->9), 14.1 KB
    __shared__ float red[NT / 64];

    const int tid  = threadIdx.x;
    const int half = tid >> 9;          // channel half: 0 or 1
    const int t8   = tid & (NT2 - 1);   // index within half
    const int gx0 = blockIdx.x * WS;
    const int gy0 = blockIdx.y * TH;
    const int n   = blockIdx.z;

    // ---- staging slot -> clamped global offset
    int gofs0, gofs1 = 0;
    {
        int r = t8 / TCOLS, c = t8 - r * TCOLS;
        gofs0 = min(max(gy0 + r - 1, 0), H_ - 1) * W_ + min(max(gx0 + c - 1, 0), W_ - 1);
        if (t8 < EXTRA) {
            int t2 = t8 + NT2;
            r = t2 / TCOLS; c = t2 - r * TCOLS;
            gofs1 = min(max(gy0 + r - 1, 0), H_ - 1) * W_ + min(max(gx0 + c - 1, 0), W_ - 1);
        }
    }

    // ---- compute mapping: vertical pixel pair
    const bool is_cp = (t8 < NPAIR);
    const int pr = t8 / WS;               // 0..3
    const int tx = t8 - pr * WS;          // 0..55
    const int r0 = (pr == 3) ? 5 : 2 * pr;   // px0 row (pair 3 overlaps row 5)
    const bool px0v = (pr < 3);              // pair 3: row-5 result is a duplicate
    const int gi0 = gy0 + r0;
    const int gj  = gx0 + tx;
    const int top = r0 * TCOLS + tx;      // upper-left slot of 4x3 window
    const int ci0 = top + TCOLS + 1;      // center slot, px0
    const int ci1 = top + 2 * TCOLS + 1;  // center slot, px1

    const float* __restrict__ plane =
        feat + ((size_t)n * C_ + (size_t)half * CHALF) * HW;

    float ss0 = 0.0f, ss1 = 0.0f;

    // ---- prologue: stage chunk 0 into buffer 0
    {
        #pragma unroll
        for (int g = 0; g < GRP; ++g) {
            float a0 = plane[(size_t)(4 * g + 0) * HW + gofs0];
            float a1 = plane[(size_t)(4 * g + 1) * HW + gofs0];
            float a2 = plane[(size_t)(4 * g + 2) * HW + gofs0];
            float a3 = plane[(size_t)(4 * g + 3) * HW + gofs0];
            ss0 += a0 * a0 + a1 * a1 + a2 * a2 + a3 * a3;
            v4f v = {a0, a1, a2, a3};
            tiles[half][0][g][t8] = v;
        }
        if (t8 < EXTRA) {
            #pragma unroll
            for (int g = 0; g < GRP; ++g) {
                float a0 = plane[(size_t)(4 * g + 0) * HW + gofs1];
                float a1 = plane[(size_t)(4 * g + 1) * HW + gofs1];
                float a2 = plane[(size_t)(4 * g + 2) * HW + gofs1];
                float a3 = plane[(size_t)(4 * g + 3) * HW + gofs1];
                ss1 += a0 * a0 + a1 * a1 + a2 * a2 + a3 * a3;
                v4f v = {a0, a1, a2, a3};
                tiles[half][0][g][t8 + NT2] = v;
            }
        }
    }
    __syncthreads();

    // accumulators: a0/a1 = px0/px1, 8 dirs {(-1,-1),(-1,0),(-1,1),(0,-1),(0,1),(1,-1),(1,0),(1,1)}
    v2f a0[8], a1[8];
    const v2f zero2 = {0.0f, 0.0f};
    #pragma unroll
    for (int d = 0; d < 8; ++d) { a0[d] = zero2; a1[d] = zero2; }

    // ---- chunk loop: 1 barrier per 8 channels per half, double-buffered
    for (int t = 0; t < NCHUNK; ++t) {
        float pv0[KCH], pv1[KCH];
        const bool more = (t + 1 < NCHUNK);
        if (more) {
            const float* p = plane + (size_t)(t + 1) * KCH * HW;
            #pragma unroll
            for (int k = 0; k < KCH; ++k) pv0[k] = p[(size_t)k * HW + gofs0];
            if (t8 < EXTRA) {
                #pragma unroll
                for (int k = 0; k < KCH; ++k) pv1[k] = p[(size_t)k * HW + gofs1];
            }
        }

        if (is_cp) {
            #pragma unroll
            for (int g = 0; g < GRP; ++g) {
                const v4f* __restrict__ cp = tiles[half][t & 1][g];
                v4f r1a = cp[top + TCOLS + 0];
                v4f r1b = cp[top + TCOLS + 1];   // = fc0 (px0 center)
                v4f r1c = cp[top + TCOLS + 2];
                v4f r2a = cp[top + 2 * TCOLS + 0];
                v4f r2b = cp[top + 2 * TCOLS + 1];  // = fc1 (px1 center)
                v4f r2c = cp[top + 2 * TCOLS + 2];
                // px0: mid row + below row
                pkfma(a0[3], r1b.lo, r1a.lo); pkfma(a0[3], r1b.hi, r1a.hi);
                pkfma(a0[4], r1b.lo, r1c.lo); pkfma(a0[4], r1b.hi, r1c.hi);
                pkfma(a0[5], r1b.lo, r2a.lo); pkfma(a0[5], r1b.hi, r2a.hi);
                pkfma(a0[6], r1b.lo, r2b.lo); pkfma(a0[6], r1b.hi, r2b.hi);
                pkfma(a0[7], r1b.lo, r2c.lo); pkfma(a0[7], r1b.hi, r2c.hi);
                // px1: above row + mid row
                pkfma(a1[0], r2b.lo, r1a.lo); pkfma(a1[0], r2b.hi, r1a.hi);
                pkfma(a1[1], r2b.lo, r1b.lo); pkfma(a1[1], r2b.hi, r1b.hi);
                pkfma(a1[2], r2b.lo, r1c.lo); pkfma(a1[2], r2b.hi, r1c.hi);
                pkfma(a1[3], r2b.lo, r2a.lo); pkfma(a1[3], r2b.hi, r2a.hi);
                pkfma(a1[4], r2b.lo, r2c.lo); pkfma(a1[4], r2b.hi, r2c.hi);
                {   // row above px0
                    v4f r0a = cp[top + 0], r0b = cp[top + 1], r0c = cp[top + 2];
                    pkfma(a0[0], r1b.lo, r0a.lo); pkfma(a0[0], r1b.hi, r0a.hi);
                    pkfma(a0[1], r1b.lo, r0b.lo); pkfma(a0[1], r1b.hi, r0b.hi);
                    pkfma(a0[2], r1b.lo, r0c.lo); pkfma(a0[2], r1b.hi, r0c.hi);
                }
                {   // row below px1
                    v4f r3a = cp[top + 3 * TCOLS + 0];
                    v4f r3b = cp[top + 3 * TCOLS + 1];
                    v4f r3c = cp[top + 3 * TCOLS + 2];
                    pkfma(a1[5], r2b.lo, r3a.lo); pkfma(a1[5], r2b.hi, r3a.hi);
                    pkfma(a1[6], r2b.lo, r3b.lo); pkfma(a1[6], r2b.hi, r3b.hi);
                    pkfma(a1[7], r2b.lo, r3c.lo); pkfma(a1[7], r2b.hi, r3c.hi);
                }
            }
        }

        if (more) {
            const int nb = (t + 1) & 1;
            #pragma unroll
            for (int g = 0; g < GRP; ++g) {
                float b0 = pv0[4 * g], b1 = pv0[4 * g + 1];
                float b2 = pv0[4 * g + 2], b3 = pv0[4 * g + 3];
                ss0 += b0 * b0 + b1 * b1 + b2 * b2 + b3 * b3;
                v4f v = {b0, b1, b2, b3};
                tiles[half][nb][g][t8] = v;
            }
            if (t8 < EXTRA) {
                #pragma unroll
                for (int g = 0; g < GRP; ++g) {
                    float b0 = pv1[4 * g], b1 = pv1[4 * g + 1];
                    float b2 = pv1[4 * g + 2], b3 = pv1[4 * g + 3];
                    ss1 += b0 * b0 + b1 * b1 + b2 * b2 + b3 * b3;
                    v4f v = {b0, b1, b2, b3};
                    tiles[half][nb][g][t8 + NT2] = v;
                }
            }
            __syncthreads();
        }
    }

    // ---- publish per-half norm partials + half1's dot partials
    ssp[half][t8] = ss0;
    if (t8 < EXTRA) ssp[half][t8 + NT2] = ss1;
    if (half == 1 && is_cp) {
        if (px0v) {
            float* d = scomb[r0 * WS + tx];
            #pragma unroll
            for (int k = 0; k < 8; ++k) d[k] = a0[k].x + a0[k].y;
        }
        float* d = scomb[(r0 + 1) * WS + tx];
        #pragma unroll
        for (int k = 0; k < 8; ++k) d[k] = a1[k].x + a1[k].y;
    }
    __syncthreads();
    if (tid < TILE_E)
        ssbuf[tid] = 1.0f / fmaxf(sqrtf(ssp[0][tid] + ssp[1][tid]), 1e-12f);
    __syncthreads();

    float lp = 0.0f;
    if (half == 0 && is_cp) {
        auto epi = [&](const v2f* a, const float* sc, int ci, int gi) -> float {
            const float s00 = a[0].x + a[0].y + sc[0];
            const float s01 = a[1].x + a[1].y + sc[1];
            const float s02 = a[2].x + a[2].y + sc[2];
            const float s10 = a[3].x + a[3].y + sc[3];
            const float s12 = a[4].x + a[4].y + sc[4];
            const float s20 = a[5].x + a[5].y + sc[5];
            const float s21 = a[6].x + a[6].y + sc[6];
            const float s22 = a[7].x + a[7].y + sc[7];
            const float ssq = ssp[0][ci] + ssp[1][ci];   // center self-dot

            const float invc = ssbuf[ci] * INV_T;
            const float l00 = s00 * invc * ssbuf[ci - TCOLS - 1];
            const float l01 = s01 * invc * ssbuf[ci - TCOLS];
            const float l02 = s02 * invc * ssbuf[ci - TCOLS + 1];
            const float l10 = s10 * invc * ssbuf[ci - 1];
            const float l11 = ssq * invc * ssbuf[ci];
            const float l12 = s12 * invc * ssbuf[ci + 1];
            const float l20 = s20 * invc * ssbuf[ci + TCOLS - 1];
            const float l21 = s21 * invc * ssbuf[ci + TCOLS];
            const float l22 = s22 * invc * ssbuf[ci + TCOLS + 1];

            const int pix = gi * W_ + gj;
            float denom = 0.f, sumlog = 0.f;
            #pragma unroll
            for (int m = 0; m < N_; ++m) {
                int d0 = dirs[((m * 2 + 0) * H_ + gi) * W_ + gj];
                int d1 = dirs[((m * 2 + 1) * H_ + gi) * W_ + gj];
                float q0 = sel3(d1, l00, l01, l02);
                float q1 = sel3(d1, l10, l11, l12);
                float q2 = sel3(d1, l20, l21, l22);
                float lm = sel3(d0, q0, q1, q2);
                int labm = labels[m * HW + pix];
                int labn = labels[n * HW + (gi + d0) * W_ + (gj + d1)];
                bool msk = (labm == labn);
                float e = msk ? __expf(lm) : 0.f;
                denom += e;
                sumlog += msk ? lm : -INFINITY;
            }
            return 8.0f * __logf(denom + 1e-6f) - sumlog;
        };
        if (px0v) lp += epi(a0, scomb[r0 * WS + tx], ci0, gi0);
        lp += epi(a1, scomb[(r0 + 1) * WS + tx], ci1, gi0 + 1);
    }

    // ---- block reduction (16 waves)
    #pragma unroll
    for (int off = 32; off > 0; off >>= 1) lp += __shfl_down(lp, off, 64);
    const int wave = tid >> 6, lane = tid & 63;
    if (lane == 0) red[wave] = lp;
    __syncthreads();
    if (tid == 0) {
        float tsum = 0.f;
        #pragma unroll
        for (int w = 0; w < NT / 64; ++w) tsum += red[w];
        const int bid = (blockIdx.z * gridDim.y + blockIdx.y) * gridDim.x + blockIdx.x;
        if (use_partial) partial[bid] = (double)tsum;
        else atomicAdd(partial, (double)tsum);
    }
}

extern "C" __global__ void __launch_bounds__(256)
dcl_final(const double* __restrict__ partial, float* __restrict__ out, int nblk)
{
    const int tid = threadIdx.x;
    double s = 0.0;
    for (int i = tid; i < nblk; i += 256) s += partial[i];
    #pragma unroll
    for (int off = 32; off > 0; off >>= 1) s += __shfl_down(s, off, 64);
    __shared__ double red[4];
    const int lane = tid & 63, wv = tid >> 6;
    if (lane == 0) red[wv] = s;
    __syncthreads();
    if (tid == 0) out[0] = (float)((red[0] + red[1] + red[2] + red[3]) / TOTAL);
}

extern "C" void kernel_launch(void* const* d_in, const int* in_sizes, int n_in,
                              void* d_out, int out_size, void* d_ws, size_t ws_size,
                              hipStream_t stream) {
    const float* feat   = (const float*)d_in[0];
    const int*   labels = (const int*)d_in[1];
    const int*   dirs   = (const int*)d_in[2];
    double* acc = (double*)d_ws;
    float*  out = (float*)d_out;

    const int use_partial = (ws_size >= (size_t)NBLK * sizeof(double)) ? 1 : 0;
    if (!use_partial) hipMemsetAsync(acc, 0, sizeof(double), stream);
    dim3 grid(W_ / WS, H_ / TH, N_);      // (2, 16, 8) = 256 blocks
    dcl_main<<<grid, NT, 0, stream>>>(feat, labels, dirs, acc, use_partial);
    dcl_final<<<1, 256, 0, stream>>>(acc, out, use_partial ? NBLK : 1);
}